// Round 1
// baseline (4903.270 us; speedup 1.0000x reference)
//
#include <hip/hip_runtime.h>

typedef unsigned int uint;

#define ROWW  4096
#define NROWS 136              // 0-63 pred bins, 64 gt-bin0, 65-127 gt bins 1-63, 128-135 replicas of gt-bin0 for pass0
#define EPSF  1e-6f

// workspace layout (bytes)
#define OFF_HC   0
#define SZ_HC    (NROWS*ROWW*4)
#define OFF_HS   (OFF_HC + SZ_HC)
#define SZ_HS    (NROWS*ROWW*4)
#define OFF_SB   (OFF_HS + SZ_HS)          // double[128]
#define OFF_SA   (OFF_SB + 128*8)          // double[128]
#define OFF_DS   (OFF_SA + 128*8)          // double[64]
#define OFF_PFX  (OFF_DS + 64*8)           // uint[128]
#define OFF_KTH  (OFF_PFX + 128*4)
#define OFF_CNT  (OFF_KTH + 128*4)
#define OFF_NB   (OFF_CNT + 128*4)
#define OFF_NA   (OFF_NB + 128*4)
#define OFF_MED  (OFF_NA + 128*4)          // float[128]
#define OFF_INV  (OFF_MED + 128*4)         // float[128]
#define WS_TOTAL (OFF_INV + 128*4)

__device__ __forceinline__ uint key_of(float f) {
    uint u = __float_as_uint(f);
    return (u & 0x80000000u) ? ~u : (u | 0x80000000u);
}
__device__ __forceinline__ float val_of(uint k) {
    uint u = (k & 0x80000000u) ? (k & 0x7fffffffu) : ~k;
    return __uint_as_float(u);
}

// ---------------- histogram pass (P = 0,1,2) ----------------
__global__ void hist_pass(const float4* __restrict__ pred4, const float4* __restrict__ gt4,
                          uint* __restrict__ hc, float* __restrict__ hs,
                          const uint* __restrict__ prefix, int n4, int P)
{
    const int rep = blockIdx.x & 7;
    const uint mmA  = (P==0) ? 0u : (P==1) ? 0xFFF00000u : 0xFFFFFF00u;  // type-A (pred rows + gt bin0)
    const int  shA  = (P==0) ? 20 : (P==1) ? 8 : 0;
    const uint dmA  = (P==2) ? 0xFFu : 0xFFFu;
    int stride = gridDim.x * blockDim.x;
    for (int i = blockIdx.x*blockDim.x + threadIdx.x; i < n4; i += stride) {
        float4 g4 = gt4[i], p4 = pred4[i];
        #pragma unroll
        for (int j = 0; j < 4; j++) {
            float g = (j==0)?g4.x:(j==1)?g4.y:(j==2)?g4.z:g4.w;
            float p = (j==0)?p4.x:(j==1)?p4.y:(j==2)?p4.z:p4.w;
            if (!(g > 0.f)) continue;                 // invalid -> excluded everywhere
            int bin = (int)(g * 64.f); if (bin > 63) bin = 63;  // g*64 is exact (pow2 scale)
            uint kp = key_of(p);
            if ((kp & mmA) == prefix[bin]) {          // pred row = bin
                uint idx = (uint)bin*ROWW + ((kp >> shA) & dmA);
                atomicAdd(&hc[idx], 1u);
                atomicAdd(&hs[idx], p);
            }
            uint kg = key_of(g);
            if (bin == 0) {                           // gt bin0: generic 12/12/8, replicated at P0
                if ((kg & mmA) == prefix[64]) {
                    int r = (P==0) ? (128 + rep) : 64;
                    uint idx = (uint)r*ROWW + ((kg >> shA) & dmA);
                    atomicAdd(&hc[idx], 1u);
                    atomicAdd(&hs[idx], g);
                }
            } else if (P == 0) {                      // gt b>=1: digit = mantissa bits [22:11]
                uint idx = (uint)(64+bin)*ROWW + ((kg >> 11) & 0xFFFu);
                atomicAdd(&hc[idx], 1u);
                atomicAdd(&hs[idx], g - (float)bin * 0.015625f);   // Sterbenz-exact
            } else if (P == 1) {                      // gt b>=1: digit = bits [10:0], exact level
                if ((kg & 0xFFFFF800u) == prefix[64+bin]) {
                    uint idx = (uint)(64+bin)*ROWW + (kg & 0x7FFu);
                    atomicAdd(&hc[idx], 1u);
                    atomicAdd(&hs[idx], g - (float)bin * 0.015625f);
                }
            }
        }
    }
}

// ---------------- per-row selection (one block per row) ----------------
__global__ void select_pass(uint* __restrict__ hc, float* __restrict__ hs,
                            uint* __restrict__ prefix, uint* __restrict__ kth,
                            uint* __restrict__ counts, uint* __restrict__ nb, uint* __restrict__ na,
                            double* __restrict__ Sb, double* __restrict__ Sa,
                            float* __restrict__ meds, float* __restrict__ invs, int P)
{
    int row = blockIdx.x;                 // 0..127
    bool typeB = (row >= 65);
    if (P == 2 && typeB) return;          // gt b>=1 rows finished at P1

    int nd, shift; bool exact;
    if (typeB) { if (P==0){nd=4096; shift=11; exact=false;} else {nd=2048; shift=0; exact=true;} }
    else       { if (P==0){nd=4096; shift=20; exact=false;}
                 else if (P==1){nd=4096; shift=8; exact=false;}
                 else {nd=256; shift=0; exact=true;} }

    const int t = threadIdx.x;            // 256 threads
    const int per = nd >> 8;              // 16 / 8 / 1
    const int be = t * per;
    const bool rep = (P==0 && row==64);

    uint  lcs[16]; float lss[16];
    uint lc = 0; double lsd = 0.0;
    for (int j = 0; j < per; j++) {
        uint c; float s;
        if (rep) { c = 0; s = 0.f;
            for (int r = 0; r < 8; r++) { int idx = (128+r)*ROWW + be + j; c += hc[idx]; s += hs[idx]; }
        } else { int idx = row*ROWW + be + j; c = hc[idx]; s = hs[idx]; }
        lcs[j] = c; lss[j] = s; lc += c; lsd += (double)s;
    }

    __shared__ uint   shc[257];
    __shared__ double shs[257];
    shc[t] = lc; shs[t] = lsd;
    __syncthreads();
    if (t == 0) {
        uint rc = 0; double rs = 0.0;
        for (int i = 0; i < 256; i++) { uint c = shc[i]; double s = shs[i]; shc[i] = rc; shs[i] = rs; rc += c; rs += s; }
        shc[256] = rc; shs[256] = rs;
    }
    __syncthreads();
    uint total = shc[256]; double totS = shs[256];

    if (P == 0 && t == 0) counts[row] = total;
    uint k = (P == 0) ? (total ? ((total-1) >> 1) : 0u) : kth[row];

    if (total) {
        uint cum = shc[t]; double sbrun = shs[t];
        for (int j = 0; j < per; j++) {
            uint c = lcs[j]; float s = lss[j];
            if (c && cum <= k && k < cum + c) {
                int dm = be + j;
                uint pfx = prefix[row];
                if (typeB && P == 0)
                    pfx = key_of((float)(row-64) * 0.015625f) & 0xFF800000u;   // constant sign+exp bits
                pfx |= ((uint)dm << shift);
                uint nb_add = cum;
                uint na_add = total - cum - c;
                double sb_new = Sb[row] + sbrun;
                double sa_new = Sa[row] + (totS - sbrun - (double)s);
                if (!exact) {
                    prefix[row] = pfx; kth[row] = k - cum;
                    nb[row] += nb_add; na[row] += na_add;
                    Sb[row] = sb_new;  Sa[row] = sa_new;
                } else {
                    float med = val_of(pfx);
                    uint cnt = counts[row];
                    double nbt = (double)(nb[row] + nb_add);
                    double nat = (double)(na[row] + na_add);
                    float basef = typeB ? (float)(row-64) * 0.015625f : 0.f;
                    double mb = (double)med - (double)basef;
                    double sumabs = (sa_new - nat*mb) + (nbt*mb - sb_new);
                    double sv = cnt ? (sumabs / (double)cnt) : 0.0;
                    meds[row] = med;
                    invs[row] = (float)(1.0 / (sv + (double)EPSF));
                }
            }
            cum += c; sbrun += (double)s;
        }
    } else if (t == 0 && exact) { meds[row] = 0.f; invs[row] = (float)(1.0/(double)EPSF); }

    __syncthreads();
    // zero this row's entries for the next pass / next launch
    for (int j = 0; j < per; j++) {
        if (rep) { for (int r = 0; r < 8; r++) { int idx = (128+r)*ROWW + be + j; hc[idx] = 0u; hs[idx] = 0.f; } }
        else     { int idx = row*ROWW + be + j; hc[idx] = 0u; hs[idx] = 0.f; }
    }
}

// ---------------- final |pred_norm - gt_norm| accumulation ----------------
__global__ void final_pass(const float4* __restrict__ pred4, const float4* __restrict__ gt4,
                           const float* __restrict__ meds, const float* __restrict__ invs,
                           double* __restrict__ ds, int n4)
{
    __shared__ float part[4][64];
    __shared__ float lmed[128], linv[128];
    for (int i = threadIdx.x; i < 256; i += blockDim.x) part[i>>6][i&63] = 0.f;
    for (int i = threadIdx.x; i < 128; i += blockDim.x) { lmed[i] = meds[i]; linv[i] = invs[i]; }
    __syncthreads();
    const int sh_id = threadIdx.x & 3;
    int stride = gridDim.x * blockDim.x;
    for (int i = blockIdx.x*blockDim.x + threadIdx.x; i < n4; i += stride) {
        float4 g4 = gt4[i], p4 = pred4[i];
        #pragma unroll
        for (int j = 0; j < 4; j++) {
            float g = (j==0)?g4.x:(j==1)?g4.y:(j==2)?g4.z:g4.w;
            float p = (j==0)?p4.x:(j==1)?p4.y:(j==2)?p4.z:p4.w;
            if (!(g > 0.f)) continue;
            int bin = (int)(g * 64.f); if (bin > 63) bin = 63;
            float pn = (p - lmed[bin])      * linv[bin];
            float gn = (g - lmed[64+bin])   * linv[64+bin];
            atomicAdd(&part[sh_id][bin], fabsf(pn - gn));
        }
    }
    __syncthreads();
    for (int i = threadIdx.x; i < 64; i += blockDim.x)
        atomicAdd(&ds[i], (double)(part[0][i]+part[1][i]+part[2][i]+part[3][i]));
}

__global__ void finish_kernel(const double* __restrict__ ds, const uint* __restrict__ counts,
                              float* __restrict__ out)
{
    __shared__ double sh[64];
    int t = threadIdx.x;
    double v = 0.0; uint c = counts[t];
    if (c) v = ds[t] / (double)c;
    sh[t] = v; __syncthreads();
    for (int o = 32; o; o >>= 1) { if (t < o) sh[t] += sh[t+o]; __syncthreads(); }
    if (t == 0) out[0] = (float)(sh[0] / 64.0);
}

extern "C" void kernel_launch(void* const* d_in, const int* in_sizes, int n_in,
                              void* d_out, int out_size, void* d_ws, size_t ws_size,
                              hipStream_t stream)
{
    const float* pred = (const float*)d_in[0];
    const float* gt   = (const float*)d_in[1];
    int n  = in_sizes[0];
    int n4 = n >> 2;

    unsigned char* ws = (unsigned char*)d_ws;
    uint*   hc  = (uint*)  (ws + OFF_HC);
    float*  hs  = (float*) (ws + OFF_HS);
    double* Sb  = (double*)(ws + OFF_SB);
    double* Sa  = (double*)(ws + OFF_SA);
    double* ds  = (double*)(ws + OFF_DS);
    uint*   pfx = (uint*)  (ws + OFF_PFX);
    uint*   kth = (uint*)  (ws + OFF_KTH);
    uint*   cnt = (uint*)  (ws + OFF_CNT);
    uint*   nb  = (uint*)  (ws + OFF_NB);
    uint*   na  = (uint*)  (ws + OFF_NA);
    float*  med = (float*) (ws + OFF_MED);
    float*  inv = (float*) (ws + OFF_INV);
    float*  out = (float*) d_out;

    hipMemsetAsync(d_ws, 0, WS_TOTAL, stream);

    for (int P = 0; P < 3; P++) {
        hist_pass<<<4096, 256, 0, stream>>>((const float4*)pred, (const float4*)gt, hc, hs, pfx, n4, P);
        select_pass<<<128, 256, 0, stream>>>(hc, hs, pfx, kth, cnt, nb, na, Sb, Sa, med, inv, P);
    }
    final_pass<<<2048, 256, 0, stream>>>((const float4*)pred, (const float4*)gt, med, inv, ds, n4);
    finish_kernel<<<1, 64, 0, stream>>>(ds, cnt, out);
}

// Round 3
// 595.120 us; speedup vs baseline: 8.2391x; 8.2391x over previous
//
#include <hip/hip_runtime.h>

typedef unsigned int uint;

#define EPSD  1e-6

// ---- pass-0 LDS histogram geometry ----
#define ND0   128                 // 7-bit digit
#define H0SZ  (128*ND0)           // 16384 counters / block (64KB LDS)
#define NB0   256
#define NT0   1024

// ---- pass-1 / survivors ----
#define NB1   2048
#define LCAP  2048                // per-block survivor staging (16KB LDS)
#define SCAP  (2u<<20)            // 2M survivor entries (16MB, overlays pc)

// ---- MAD / final ----
#define NBM   512
#define NTM   512
#define NBF   1024

// ---- workspace layout (bytes) ----
#define OFF_H1A  0u                               // uint[65*4096]      ~1.06MB
#define SZ_H1A   (65u*4096u*4u)
#define OFF_H1B  (OFF_H1A + SZ_H1A)               // packed u16[63*65536] = uint[63*32768] ~8.26MB
#define SZ_H1B   (63u*32768u*4u)
#define OFF_H2   (OFF_H1B + SZ_H1B)               // uint[65*8192]      ~2.13MB
#define SZ_H2    (65u*8192u*4u)
#define OFF_PFX  (OFF_H2 + SZ_H2)                 // uint[128] (+pad)
#define OFF_KTH  (OFF_PFX + 512u)
#define OFF_CNT  (OFF_KTH + 512u)
#define OFF_GCT  (OFF_CNT + 512u)
#define OFF_MED  (OFF_GCT + 512u)                 // float[128]
#define OFF_INV  (OFF_MED + 512u)                 // float[128]
#define MEMSET_LEN (OFF_INV + 512u)
#define OFF_PC   ((MEMSET_LEN + 255u) & ~255u)    // uint[NB0*H0SZ] 16MB (fully overwritten)
#define SZ_PC    ((uint)NB0*H0SZ*4u)
#define OFF_GB   OFF_PC                           // uint2[SCAP] 16MB — reuses pc after sel P0
#define OFF_MP   (OFF_PC + SZ_PC)                 // float[NBM*128] 256KB
#define OFF_FP   (OFF_MP + (uint)NBM*128u*4u)     // float[NBF*64]  256KB

__device__ __forceinline__ uint key_of(float f) {
    uint u = __float_as_uint(f);
    return (u & 0x80000000u) ? ~u : (u | 0x80000000u);
}
__device__ __forceinline__ float val_of(uint k) {
    uint u = (k & 0x80000000u) ? (k & 0x7fffffffu) : ~k;
    return __uint_as_float(u);
}
__device__ __forceinline__ float elem(const float4& v, int j) {
    return (j==0)?v.x:(j==1)?v.y:(j==2)?v.z:v.w;
}

// ================= P0: 7-bit LDS histogram, counts only =================
__global__ __launch_bounds__(NT0) void p0_hist(const float4* __restrict__ pred4,
                                               const float4* __restrict__ gt4,
                                               uint* __restrict__ pcnt, int n4)
{
    __shared__ uint h[H0SZ];
    for (int i = threadIdx.x; i < H0SZ; i += NT0) h[i] = 0u;
    __syncthreads();
    int stride = gridDim.x * blockDim.x;
    for (int i = blockIdx.x*blockDim.x + threadIdx.x; i < n4; i += stride) {
        float4 g4 = gt4[i], p4 = pred4[i];
        #pragma unroll
        for (int j = 0; j < 4; j++) {
            float g = elem(g4,j), p = elem(p4,j);
            if (!(g > 0.f)) continue;
            int bin = (int)(g * 64.f); if (bin > 63) bin = 63;
            uint kp = key_of(p);
            atomicAdd(&h[(uint)bin*ND0 + ((kp>>25) ^ ((uint)bin & 31u))], 1u);
            uint kg = key_of(g);
            uint gr = 64u + (uint)bin;
            uint dg = bin ? ((kg>>16) & 0x7Fu) : (kg>>25);
            atomicAdd(&h[gr*ND0 + (dg ^ (gr & 31u))], 1u);
        }
    }
    __syncthreads();
    uint* dst = pcnt + (size_t)blockIdx.x * H0SZ;
    for (int i = threadIdx.x; i < H0SZ; i += NT0) dst[i] = h[i];
}

// ================= unified select pass (two-phase, rescan) =================
__global__ void sel_pass(const uint* __restrict__ pcnt, const uint* __restrict__ h1A,
                         const uint* __restrict__ h1B, const uint* __restrict__ h2,
                         uint* __restrict__ pfx, uint* __restrict__ kth,
                         uint* __restrict__ cnts, float* __restrict__ meds, int P)
{
    int row = blockIdx.x;                  // P0/P1: 0..127, P2: 0..64
    bool tB = (row >= 65);
    int nd, shift; bool exact;
    const uint* src = nullptr; size_t sbase = 0; bool packed = false;
    if (P == 0)      { nd = ND0; shift = tB ? 16 : 25; exact = false; }
    else if (P == 1) {
        if (tB) { nd = 65536; shift = 0;  exact = true;  src = h1B; sbase = (size_t)(row-65)*32768u; packed = true; }
        else    { nd = 4096;  shift = 13; exact = false; src = h1A; sbase = (size_t)row*4096u; }
    } else           { nd = 8192; shift = 0; exact = true; src = h2; sbase = (size_t)row*8192u; }

    int t = threadIdx.x;                   // 256 threads
    int per = (nd + 255) >> 8;
    int d0 = t * per;

    // phase 1: per-thread digit-range sums
    uint lc = 0;
    for (int j = 0; j < per; j++) {
        int d = d0 + j; if (d >= nd) break;
        uint c;
        if (P == 0) {
            int idx = row*ND0 + (d ^ (row & 31));
            c = 0;
            for (int p = 0; p < NB0; p++) c += pcnt[(size_t)p*H0SZ + idx];
        } else if (packed) c = (src[sbase + (d >> 1)] >> ((d & 1) * 16)) & 0xFFFFu;
        else               c = src[sbase + d];
        lc += c;
    }
    __shared__ uint shc[257];
    shc[t] = lc;
    __syncthreads();
    if (t == 0) { uint r = 0; for (int i = 0; i < 256; i++) { uint c = shc[i]; shc[i] = r; r += c; } shc[256] = r; }
    __syncthreads();
    uint total = shc[256];
    if (P == 0 && t == 0) cnts[row] = total;
    uint k = (P == 0) ? (total ? ((total-1u) >> 1) : 0u) : kth[row];
    if (!total) return;

    // phase 2: owning thread rescans its range
    uint cum = shc[t];
    if (k >= cum && k < cum + lc) {
        for (int j = 0; j < per; j++) {
            int d = d0 + j;
            uint c;
            if (P == 0) {
                int idx = row*ND0 + (d ^ (row & 31));
                c = 0;
                for (int p = 0; p < NB0; p++) c += pcnt[(size_t)p*H0SZ + idx];
            } else if (packed) c = (src[sbase + (d >> 1)] >> ((d & 1) * 16)) & 0xFFFFu;
            else               c = src[sbase + d];
            if (c && k < cum + c) {
                uint np;
                if (P == 0) {
                    uint base = tB ? (key_of((float)(row-64) * 0.015625f) & 0xFF800000u) : 0u;
                    np = base | ((uint)d << shift);
                } else np = pfx[row] | ((uint)d << shift);
                if (!exact) { pfx[row] = np; kth[row] = k - cum; }
                else        meds[row] = val_of(np);
                break;
            }
            cum += c;
        }
    }
}

// ================= P1: filtered hists + type-A survivor compaction =================
__global__ void p1_hist(const float4* __restrict__ pred4, const float4* __restrict__ gt4,
                        const uint* __restrict__ pfx, uint* __restrict__ h1A,
                        uint* __restrict__ h1B, uint2* __restrict__ gbuf,
                        uint* __restrict__ gcnt, int n4)
{
    __shared__ uint pf[128];
    __shared__ uint2 sbuf[LCAP];
    __shared__ uint lcnt, gbase;
    if (threadIdx.x == 0) lcnt = 0u;
    for (int i = threadIdx.x; i < 128; i += blockDim.x) pf[i] = pfx[i];
    __syncthreads();

    int stride = gridDim.x * blockDim.x;
    for (int i = blockIdx.x*blockDim.x + threadIdx.x; i < n4; i += stride) {
        float4 g4 = gt4[i], p4 = pred4[i];
        #pragma unroll
        for (int j = 0; j < 4; j++) {
            float g = elem(g4,j), p = elem(p4,j);
            if (!(g > 0.f)) continue;
            int bin = (int)(g * 64.f); if (bin > 63) bin = 63;
            uint kp = key_of(p);
            if ((kp & 0xFE000000u) == pf[bin]) {
                atomicAdd(&h1A[(size_t)bin*4096 + ((kp>>13) & 0xFFFu)], 1u);
                uint li = atomicAdd(&lcnt, 1u);
                if (li < LCAP) sbuf[li] = make_uint2(kp, (uint)bin);
                else { uint gi = atomicAdd(gcnt, 1u); if (gi < SCAP) gbuf[gi] = make_uint2(kp, (uint)bin); }
            }
            uint kg = key_of(g);
            if (bin == 0) {
                if ((kg & 0xFE000000u) == pf[64]) {
                    atomicAdd(&h1A[(size_t)64*4096 + ((kg>>13) & 0xFFFu)], 1u);
                    uint li = atomicAdd(&lcnt, 1u);
                    if (li < LCAP) sbuf[li] = make_uint2(kg, 64u);
                    else { uint gi = atomicAdd(gcnt, 1u); if (gi < SCAP) gbuf[gi] = make_uint2(kg, 64u); }
                }
            } else {
                if ((kg & 0xFFFF0000u) == pf[64 + bin]) {
                    uint d = kg & 0xFFFFu;
                    atomicAdd(&h1B[(size_t)(bin-1)*32768 + (d >> 1)], (d & 1u) ? 65536u : 1u);
                }
            }
        }
    }
    __syncthreads();
    if (threadIdx.x == 0) {
        uint c = lcnt; if (c > LCAP) c = LCAP;
        gbase = atomicAdd(gcnt, c);
    }
    __syncthreads();
    uint c = lcnt; if (c > LCAP) c = LCAP;
    for (uint i = threadIdx.x; i < c; i += blockDim.x) {
        uint gi = gbase + i;
        if (gi < SCAP) gbuf[gi] = sbuf[i];
    }
}

// ================= P2: compacted type-A survivors -> final 13-bit hist =================
__global__ void p2_compact(const uint2* __restrict__ gbuf, const uint* __restrict__ gcnt,
                           const uint* __restrict__ pfx, uint* __restrict__ h2)
{
    uint n = *gcnt; if (n > SCAP) n = SCAP;
    uint stride = gridDim.x * blockDim.x;
    for (uint i = blockIdx.x*blockDim.x + threadIdx.x; i < n; i += stride) {
        uint2 e = gbuf[i];
        if ((e.x & 0xFFFFE000u) == pfx[e.y])
            atomicAdd(&h2[(size_t)e.y*8192 + (e.x & 0x1FFFu)], 1u);
    }
}

// ================= MAD pass: sum |v - med| per row =================
__global__ void mad_pass(const float4* __restrict__ pred4, const float4* __restrict__ gt4,
                         const float* __restrict__ meds, float* __restrict__ madp, int n4)
{
    __shared__ float part[4][128];
    __shared__ float lm[128];
    for (int i = threadIdx.x; i < 512; i += blockDim.x) part[i>>7][i&127] = 0.f;
    for (int i = threadIdx.x; i < 128; i += blockDim.x) lm[i] = meds[i];
    __syncthreads();
    int r4 = threadIdx.x & 3;
    int stride = gridDim.x * blockDim.x;
    for (int i = blockIdx.x*blockDim.x + threadIdx.x; i < n4; i += stride) {
        float4 g4 = gt4[i], p4 = pred4[i];
        #pragma unroll
        for (int j = 0; j < 4; j++) {
            float g = elem(g4,j), p = elem(p4,j);
            if (!(g > 0.f)) continue;
            int bin = (int)(g * 64.f); if (bin > 63) bin = 63;
            atomicAdd(&part[r4][bin],      fabsf(p - lm[bin]));
            atomicAdd(&part[r4][64 + bin], fabsf(g - lm[64 + bin]));
        }
    }
    __syncthreads();
    for (int i = threadIdx.x; i < 128; i += blockDim.x)
        madp[(size_t)blockIdx.x*128 + i] = part[0][i] + part[1][i] + part[2][i] + part[3][i];
}

__global__ void sel3(const float* __restrict__ madp, const uint* __restrict__ cnts,
                     float* __restrict__ inv)
{
    int t = threadIdx.x;                   // 128
    double s = 0.0;
    for (int b = 0; b < NBM; b++) s += (double)madp[(size_t)b*128 + t];
    uint c = cnts[t];
    double sv = c ? (s / (double)c) : 0.0;
    inv[t] = (float)(1.0 / (sv + EPSD));
}

// ================= final |pred_norm - gt_norm| =================
__global__ void final_pass(const float4* __restrict__ pred4, const float4* __restrict__ gt4,
                           const float* __restrict__ meds, const float* __restrict__ invs,
                           float* __restrict__ fpart, int n4)
{
    __shared__ float part[8][64];
    __shared__ float lm[128], li[128];
    for (int i = threadIdx.x; i < 512; i += blockDim.x) part[i>>6][i&63] = 0.f;
    for (int i = threadIdx.x; i < 128; i += blockDim.x) { lm[i] = meds[i]; li[i] = invs[i]; }
    __syncthreads();
    int r8 = threadIdx.x & 7;
    int stride = gridDim.x * blockDim.x;
    for (int i = blockIdx.x*blockDim.x + threadIdx.x; i < n4; i += stride) {
        float4 g4 = gt4[i], p4 = pred4[i];
        #pragma unroll
        for (int j = 0; j < 4; j++) {
            float g = elem(g4,j), p = elem(p4,j);
            if (!(g > 0.f)) continue;
            int bin = (int)(g * 64.f); if (bin > 63) bin = 63;
            float pn = (p - lm[bin])      * li[bin];
            float gn = (g - lm[64 + bin]) * li[64 + bin];
            atomicAdd(&part[r8][bin], fabsf(pn - gn));
        }
    }
    __syncthreads();
    for (int i = threadIdx.x; i < 64; i += blockDim.x) {
        float s = 0.f;
        #pragma unroll
        for (int r = 0; r < 8; r++) s += part[r][i];
        fpart[(size_t)blockIdx.x*64 + i] = s;
    }
}

__global__ void finish_kernel(const float* __restrict__ fpart, const uint* __restrict__ cnts,
                              float* __restrict__ out)
{
    __shared__ double sh[64];
    int t = threadIdx.x;                   // 64
    double s = 0.0;
    for (int b = 0; b < NBF; b++) s += (double)fpart[(size_t)b*64 + t];
    uint c = cnts[t];
    sh[t] = c ? (s / (double)c) : 0.0;
    __syncthreads();
    for (int o = 32; o; o >>= 1) { if (t < o) sh[t] += sh[t + o]; __syncthreads(); }
    if (t == 0) out[0] = (float)(sh[0] / 64.0);
}

extern "C" void kernel_launch(void* const* d_in, const int* in_sizes, int n_in,
                              void* d_out, int out_size, void* d_ws, size_t ws_size,
                              hipStream_t stream)
{
    const float* pred = (const float*)d_in[0];
    const float* gt   = (const float*)d_in[1];
    int n  = in_sizes[0];
    int n4 = n >> 2;

    unsigned char* ws = (unsigned char*)d_ws;
    uint*  h1A  = (uint*) (ws + OFF_H1A);
    uint*  h1B  = (uint*) (ws + OFF_H1B);
    uint*  h2   = (uint*) (ws + OFF_H2);
    uint*  pfx  = (uint*) (ws + OFF_PFX);
    uint*  kth  = (uint*) (ws + OFF_KTH);
    uint*  cnt  = (uint*) (ws + OFF_CNT);
    uint*  gct  = (uint*) (ws + OFF_GCT);
    float* med  = (float*)(ws + OFF_MED);
    float* inv  = (float*)(ws + OFF_INV);
    uint*  pc   = (uint*) (ws + OFF_PC);
    uint2* gb   = (uint2*)(ws + OFF_GB);
    float* mp   = (float*)(ws + OFF_MP);
    float* fp   = (float*)(ws + OFF_FP);
    float* out  = (float*)d_out;

    hipMemsetAsync(ws, 0, MEMSET_LEN, stream);

    p0_hist<<<NB0, NT0, 0, stream>>>((const float4*)pred, (const float4*)gt, pc, n4);
    sel_pass<<<128, 256, 0, stream>>>(pc, h1A, h1B, h2, pfx, kth, cnt, med, 0);
    p1_hist<<<NB1, 256, 0, stream>>>((const float4*)pred, (const float4*)gt, pfx, h1A, h1B, gb, gct, n4);
    sel_pass<<<128, 256, 0, stream>>>(pc, h1A, h1B, h2, pfx, kth, cnt, med, 1);
    p2_compact<<<256, 256, 0, stream>>>(gb, gct, pfx, h2);
    sel_pass<<<65, 256, 0, stream>>>(pc, h1A, h1B, h2, pfx, kth, cnt, med, 2);
    mad_pass<<<NBM, NTM, 0, stream>>>((const float4*)pred, (const float4*)gt, med, mp, n4);
    sel3<<<1, 128, 0, stream>>>(mp, cnt, inv);
    final_pass<<<NBF, 256, 0, stream>>>((const float4*)pred, (const float4*)gt, med, inv, fp, n4);
    finish_kernel<<<1, 64, 0, stream>>>(fp, cnt, out);
}

// Round 4
// 584.899 us; speedup vs baseline: 8.3831x; 1.0175x over previous
//
#include <hip/hip_runtime.h>

typedef unsigned int uint;

#define EPSD  1e-6

// ---- pass-0 LDS histogram geometry ----
#define ND0   128                 // 7-bit digit
#define H0SZ  (128*ND0)           // 16384 counters / block (64KB LDS)
#define NB0   256
#define NT0   1024

// ---- pass-1 / survivors ----
#define NB1   2048
#define LCAP  2048                // per-block survivor staging (16KB LDS)
#define SCAP  (2u<<20)            // 2M survivor entries (16MB, overlays pc)

// ---- MAD / final ----
#define NBM   512
#define NTM   512
#define NBF   512
#define NTF   512

// ---- workspace layout (bytes) ----
#define OFF_H1A  0u                               // uint[65*4096]      ~1.06MB
#define SZ_H1A   (65u*4096u*4u)
#define OFF_H1B  (OFF_H1A + SZ_H1A)               // packed u16[63*65536] = uint[63*32768] ~8.26MB
#define SZ_H1B   (63u*32768u*4u)
#define OFF_H2   (OFF_H1B + SZ_H1B)               // uint[65*8192]      ~2.13MB
#define SZ_H2    (65u*8192u*4u)
#define OFF_PFX  (OFF_H2 + SZ_H2)                 // uint[128] (+pad)
#define OFF_KTH  (OFF_PFX + 512u)
#define OFF_CNT  (OFF_KTH + 512u)
#define OFF_GCT  (OFF_CNT + 512u)
#define OFF_MED  (OFF_GCT + 512u)                 // float[128]
#define OFF_INV  (OFF_MED + 512u)                 // float[128]
#define MEMSET_LEN (OFF_INV + 512u)
#define OFF_PC   ((MEMSET_LEN + 255u) & ~255u)    // uint[NB0*H0SZ] 16MB (fully overwritten)
#define SZ_PC    ((uint)NB0*H0SZ*4u)
#define OFF_GB   OFF_PC                           // uint2[SCAP] 16MB — reuses pc after sel P0
#define OFF_MP   (OFF_PC + SZ_PC)                 // float[NBM*128] 256KB
#define OFF_FP   (OFF_MP + (uint)NBM*128u*4u)     // float[NBF*64]  128KB

__device__ __forceinline__ uint key_of(float f) {
    uint u = __float_as_uint(f);
    return (u & 0x80000000u) ? ~u : (u | 0x80000000u);
}
__device__ __forceinline__ float val_of(uint k) {
    uint u = (k & 0x80000000u) ? (k & 0x7fffffffu) : ~k;
    return __uint_as_float(u);
}
__device__ __forceinline__ float elem(const float4& v, int j) {
    return (j==0)?v.x:(j==1)?v.y:(j==2)?v.z:v.w;
}

// ================= P0: 7-bit LDS histogram, counts only =================
__global__ __launch_bounds__(NT0) void p0_hist(const float4* __restrict__ pred4,
                                               const float4* __restrict__ gt4,
                                               uint* __restrict__ pcnt, int n4)
{
    __shared__ uint h[H0SZ];
    for (int i = threadIdx.x; i < H0SZ; i += NT0) h[i] = 0u;
    __syncthreads();
    int stride = gridDim.x * blockDim.x;
    for (int i = blockIdx.x*blockDim.x + threadIdx.x; i < n4; i += stride) {
        float4 g4 = gt4[i], p4 = pred4[i];
        #pragma unroll
        for (int j = 0; j < 4; j++) {
            float g = elem(g4,j), p = elem(p4,j);
            if (!(g > 0.f)) continue;
            int bin = (int)(g * 64.f); if (bin > 63) bin = 63;
            uint kp = key_of(p);
            atomicAdd(&h[(uint)bin*ND0 + ((kp>>25) ^ ((uint)bin & 31u))], 1u);
            uint kg = key_of(g);
            uint gr = 64u + (uint)bin;
            uint dg = bin ? ((kg>>16) & 0x7Fu) : (kg>>25);
            atomicAdd(&h[gr*ND0 + (dg ^ (gr & 31u))], 1u);
        }
    }
    __syncthreads();
    uint* dst = pcnt + (size_t)blockIdx.x * H0SZ;
    for (int i = threadIdx.x; i < H0SZ; i += NT0) dst[i] = h[i];
}

// ================= unified select pass (two-phase, rescan) =================
__global__ void sel_pass(const uint* __restrict__ pcnt, const uint* __restrict__ h1A,
                         const uint* __restrict__ h1B, const uint* __restrict__ h2,
                         uint* __restrict__ pfx, uint* __restrict__ kth,
                         uint* __restrict__ cnts, float* __restrict__ meds, int P)
{
    int row = blockIdx.x;                  // P0/P1: 0..127, P2: 0..64
    bool tB = (row >= 65);
    int nd, shift; bool exact;
    const uint* src = nullptr; size_t sbase = 0; bool packed = false;
    if (P == 0)      { nd = ND0; shift = tB ? 16 : 25; exact = false; }
    else if (P == 1) {
        if (tB) { nd = 65536; shift = 0;  exact = true;  src = h1B; sbase = (size_t)(row-65)*32768u; packed = true; }
        else    { nd = 4096;  shift = 13; exact = false; src = h1A; sbase = (size_t)row*4096u; }
    } else           { nd = 8192; shift = 0; exact = true; src = h2; sbase = (size_t)row*8192u; }

    int t = threadIdx.x;                   // 256 threads
    int per = (nd + 255) >> 8;
    int d0 = t * per;

    // phase 1: per-thread digit-range sums
    uint lc = 0;
    for (int j = 0; j < per; j++) {
        int d = d0 + j; if (d >= nd) break;
        uint c;
        if (P == 0) {
            int idx = row*ND0 + (d ^ (row & 31));
            c = 0;
            for (int p = 0; p < NB0; p++) c += pcnt[(size_t)p*H0SZ + idx];
        } else if (packed) c = (src[sbase + (d >> 1)] >> ((d & 1) * 16)) & 0xFFFFu;
        else               c = src[sbase + d];
        lc += c;
    }
    __shared__ uint shc[257];
    shc[t] = lc;
    __syncthreads();
    if (t == 0) { uint r = 0; for (int i = 0; i < 256; i++) { uint c = shc[i]; shc[i] = r; r += c; } shc[256] = r; }
    __syncthreads();
    uint total = shc[256];
    if (P == 0 && t == 0) cnts[row] = total;
    uint k = (P == 0) ? (total ? ((total-1u) >> 1) : 0u) : kth[row];
    if (!total) return;

    // phase 2: owning thread rescans its range
    uint cum = shc[t];
    if (k >= cum && k < cum + lc) {
        for (int j = 0; j < per; j++) {
            int d = d0 + j;
            uint c;
            if (P == 0) {
                int idx = row*ND0 + (d ^ (row & 31));
                c = 0;
                for (int p = 0; p < NB0; p++) c += pcnt[(size_t)p*H0SZ + idx];
            } else if (packed) c = (src[sbase + (d >> 1)] >> ((d & 1) * 16)) & 0xFFFFu;
            else               c = src[sbase + d];
            if (c && k < cum + c) {
                uint np;
                if (P == 0) {
                    uint base = tB ? (key_of((float)(row-64) * 0.015625f) & 0xFF800000u) : 0u;
                    np = base | ((uint)d << shift);
                } else np = pfx[row] | ((uint)d << shift);
                if (!exact) { pfx[row] = np; kth[row] = k - cum; }
                else        meds[row] = val_of(np);
                break;
            }
            cum += c;
        }
    }
}

// ================= P1: filtered hists + type-A survivor compaction =================
__global__ void p1_hist(const float4* __restrict__ pred4, const float4* __restrict__ gt4,
                        const uint* __restrict__ pfx, uint* __restrict__ h1A,
                        uint* __restrict__ h1B, uint2* __restrict__ gbuf,
                        uint* __restrict__ gcnt, int n4)
{
    __shared__ uint pf[128];
    __shared__ uint2 sbuf[LCAP];
    __shared__ uint lcnt, gbase;
    if (threadIdx.x == 0) lcnt = 0u;
    for (int i = threadIdx.x; i < 128; i += blockDim.x) pf[i] = pfx[i];
    __syncthreads();

    int stride = gridDim.x * blockDim.x;
    for (int i = blockIdx.x*blockDim.x + threadIdx.x; i < n4; i += stride) {
        float4 g4 = gt4[i], p4 = pred4[i];
        #pragma unroll
        for (int j = 0; j < 4; j++) {
            float g = elem(g4,j), p = elem(p4,j);
            if (!(g > 0.f)) continue;
            int bin = (int)(g * 64.f); if (bin > 63) bin = 63;
            uint kp = key_of(p);
            if ((kp & 0xFE000000u) == pf[bin]) {
                atomicAdd(&h1A[(size_t)bin*4096 + ((kp>>13) & 0xFFFu)], 1u);
                uint li = atomicAdd(&lcnt, 1u);
                if (li < LCAP) sbuf[li] = make_uint2(kp, (uint)bin);
                else { uint gi = atomicAdd(gcnt, 1u); if (gi < SCAP) gbuf[gi] = make_uint2(kp, (uint)bin); }
            }
            uint kg = key_of(g);
            if (bin == 0) {
                if ((kg & 0xFE000000u) == pf[64]) {
                    atomicAdd(&h1A[(size_t)64*4096 + ((kg>>13) & 0xFFFu)], 1u);
                    uint li = atomicAdd(&lcnt, 1u);
                    if (li < LCAP) sbuf[li] = make_uint2(kg, 64u);
                    else { uint gi = atomicAdd(gcnt, 1u); if (gi < SCAP) gbuf[gi] = make_uint2(kg, 64u); }
                }
            } else {
                if ((kg & 0xFFFF0000u) == pf[64 + bin]) {
                    uint d = kg & 0xFFFFu;
                    atomicAdd(&h1B[(size_t)(bin-1)*32768 + (d >> 1)], (d & 1u) ? 65536u : 1u);
                }
            }
        }
    }
    __syncthreads();
    if (threadIdx.x == 0) {
        uint c = lcnt; if (c > LCAP) c = LCAP;
        gbase = atomicAdd(gcnt, c);
    }
    __syncthreads();
    uint c = lcnt; if (c > LCAP) c = LCAP;
    for (uint i = threadIdx.x; i < c; i += blockDim.x) {
        uint gi = gbase + i;
        if (gi < SCAP) gbuf[gi] = sbuf[i];
    }
}

// ================= P2: compacted type-A survivors -> final 13-bit hist =================
__global__ void p2_compact(const uint2* __restrict__ gbuf, const uint* __restrict__ gcnt,
                           const uint* __restrict__ pfx, uint* __restrict__ h2)
{
    uint n = *gcnt; if (n > SCAP) n = SCAP;
    uint stride = gridDim.x * blockDim.x;
    for (uint i = blockIdx.x*blockDim.x + threadIdx.x; i < n; i += stride) {
        uint2 e = gbuf[i];
        if ((e.x & 0xFFFFE000u) == pfx[e.y])
            atomicAdd(&h2[(size_t)e.y*8192 + (e.x & 0x1FFFu)], 1u);
    }
}

// ================= MAD pass: lane-column-striped LDS accumulators =================
__global__ __launch_bounds__(NTM) void mad_pass(const float4* __restrict__ pred4,
                                                const float4* __restrict__ gt4,
                                                const float* __restrict__ meds,
                                                float* __restrict__ madp, int n4)
{
    __shared__ __align__(16) float acc[128][64];   // bank = lane%32 -> conflict-free
    __shared__ float mp_[64], mg_[64];
    for (int i = threadIdx.x; i < 128*64; i += NTM) ((float*)acc)[i] = 0.f;
    if (threadIdx.x < 64) { mp_[threadIdx.x] = meds[threadIdx.x]; mg_[threadIdx.x] = meds[64 + threadIdx.x]; }
    __syncthreads();
    const int lane = threadIdx.x & 63;
    int stride = gridDim.x * blockDim.x;
    for (int i = blockIdx.x*blockDim.x + threadIdx.x; i < n4; i += stride) {
        float4 g4 = gt4[i], p4 = pred4[i];
        #pragma unroll
        for (int j = 0; j < 4; j++) {
            float g = elem(g4,j), p = elem(p4,j);
            if (!(g > 0.f)) continue;
            int bin = (int)(g * 64.f); if (bin > 63) bin = 63;
            atomicAdd(&acc[bin][lane],      fabsf(p - mp_[bin]));
            atomicAdd(&acc[64 + bin][lane], fabsf(g - mg_[bin]));
        }
    }
    __syncthreads();
    const float4* a4 = (const float4*)&acc[0][0];
    #pragma unroll
    for (int it = 0; it < (128*64/4)/NTM; ++it) {
        int f = it*NTM + threadIdx.x;              // float4 index; 16 per row
        float4 v = a4[f];
        float s = v.x + v.y + v.z + v.w;
        s += __shfl_xor(s, 1); s += __shfl_xor(s, 2);
        s += __shfl_xor(s, 4); s += __shfl_xor(s, 8);
        if ((f & 15) == 0) madp[(size_t)blockIdx.x*128 + (f >> 4)] = s;
    }
}

__global__ void sel3(const float* __restrict__ madp, const uint* __restrict__ cnts,
                     float* __restrict__ inv)
{
    int t = threadIdx.x;                   // 128
    double s = 0.0;
    for (int b = 0; b < NBM; b++) s += (double)madp[(size_t)b*128 + t];
    uint c = cnts[t];
    double sv = c ? (s / (double)c) : 0.0;
    inv[t] = (float)(1.0 / (sv + EPSD));
}

// ================= final |pred_norm - gt_norm| =================
__global__ __launch_bounds__(NTF) void final_pass(const float4* __restrict__ pred4,
                                                  const float4* __restrict__ gt4,
                                                  const float* __restrict__ meds,
                                                  const float* __restrict__ invs,
                                                  float* __restrict__ fpart, int n4)
{
    __shared__ __align__(16) float acc[64][64];    // bank = lane%32 -> conflict-free
    __shared__ float ipt[64], igt[64], Ct[64];
    for (int i = threadIdx.x; i < 64*64; i += NTF) ((float*)acc)[i] = 0.f;
    if (threadIdx.x < 64) {
        int b = threadIdx.x;
        float ip = invs[b], ig = invs[64 + b];
        ipt[b] = ip; igt[b] = ig;
        Ct[b] = meds[b]*ip - meds[64 + b]*ig;
    }
    __syncthreads();
    const int lane = threadIdx.x & 63;
    int stride = gridDim.x * blockDim.x;
    for (int i = blockIdx.x*blockDim.x + threadIdx.x; i < n4; i += stride) {
        float4 g4 = gt4[i], p4 = pred4[i];
        #pragma unroll
        for (int j = 0; j < 4; j++) {
            float g = elem(g4,j), p = elem(p4,j);
            if (!(g > 0.f)) continue;
            int bin = (int)(g * 64.f); if (bin > 63) bin = 63;
            float d = p*ipt[bin] - g*igt[bin] - Ct[bin];
            atomicAdd(&acc[bin][lane], fabsf(d));
        }
    }
    __syncthreads();
    const float4* a4 = (const float4*)&acc[0][0];
    #pragma unroll
    for (int it = 0; it < (64*64/4)/NTF; ++it) {
        int f = it*NTF + threadIdx.x;
        float4 v = a4[f];
        float s = v.x + v.y + v.z + v.w;
        s += __shfl_xor(s, 1); s += __shfl_xor(s, 2);
        s += __shfl_xor(s, 4); s += __shfl_xor(s, 8);
        if ((f & 15) == 0) fpart[(size_t)blockIdx.x*64 + (f >> 4)] = s;
    }
}

__global__ void finish_kernel(const float* __restrict__ fpart, const uint* __restrict__ cnts,
                              float* __restrict__ out)
{
    __shared__ double sh[64];
    int t = threadIdx.x;                   // 64
    double s = 0.0;
    for (int b = 0; b < NBF; b++) s += (double)fpart[(size_t)b*64 + t];
    uint c = cnts[t];
    sh[t] = c ? (s / (double)c) : 0.0;
    __syncthreads();
    for (int o = 32; o; o >>= 1) { if (t < o) sh[t] += sh[t + o]; __syncthreads(); }
    if (t == 0) out[0] = (float)(sh[0] / 64.0);
}

extern "C" void kernel_launch(void* const* d_in, const int* in_sizes, int n_in,
                              void* d_out, int out_size, void* d_ws, size_t ws_size,
                              hipStream_t stream)
{
    const float* pred = (const float*)d_in[0];
    const float* gt   = (const float*)d_in[1];
    int n  = in_sizes[0];
    int n4 = n >> 2;

    unsigned char* ws = (unsigned char*)d_ws;
    uint*  h1A  = (uint*) (ws + OFF_H1A);
    uint*  h1B  = (uint*) (ws + OFF_H1B);
    uint*  h2   = (uint*) (ws + OFF_H2);
    uint*  pfx  = (uint*) (ws + OFF_PFX);
    uint*  kth  = (uint*) (ws + OFF_KTH);
    uint*  cnt  = (uint*) (ws + OFF_CNT);
    uint*  gct  = (uint*) (ws + OFF_GCT);
    float* med  = (float*)(ws + OFF_MED);
    float* inv  = (float*)(ws + OFF_INV);
    uint*  pc   = (uint*) (ws + OFF_PC);
    uint2* gb   = (uint2*)(ws + OFF_GB);
    float* mp   = (float*)(ws + OFF_MP);
    float* fp   = (float*)(ws + OFF_FP);
    float* out  = (float*)d_out;

    hipMemsetAsync(ws, 0, MEMSET_LEN, stream);

    p0_hist<<<NB0, NT0, 0, stream>>>((const float4*)pred, (const float4*)gt, pc, n4);
    sel_pass<<<128, 256, 0, stream>>>(pc, h1A, h1B, h2, pfx, kth, cnt, med, 0);
    p1_hist<<<NB1, 256, 0, stream>>>((const float4*)pred, (const float4*)gt, pfx, h1A, h1B, gb, gct, n4);
    sel_pass<<<128, 256, 0, stream>>>(pc, h1A, h1B, h2, pfx, kth, cnt, med, 1);
    p2_compact<<<256, 256, 0, stream>>>(gb, gct, pfx, h2);
    sel_pass<<<65, 256, 0, stream>>>(pc, h1A, h1B, h2, pfx, kth, cnt, med, 2);
    mad_pass<<<NBM, NTM, 0, stream>>>((const float4*)pred, (const float4*)gt, med, mp, n4);
    sel3<<<1, 128, 0, stream>>>(mp, cnt, inv);
    final_pass<<<NBF, NTF, 0, stream>>>((const float4*)pred, (const float4*)gt, med, inv, fp, n4);
    finish_kernel<<<1, 64, 0, stream>>>(fp, cnt, out);
}

// Round 5
// 485.126 us; speedup vs baseline: 10.1072x; 1.2057x over previous
//
#include <hip/hip_runtime.h>

typedef unsigned int uint;
typedef unsigned long long ull;

#define EPSD  1e-6

// ---- pass-0 LDS histogram geometry ----
#define ND0   128                 // 7-bit digit
#define H0SZ  (128*ND0)           // 16384 counters / block (64KB LDS)
#define NB0   256
#define NT0   1024

// ---- pass-1 / survivors ----
#define NB1   2048
#define LCAP  2048                // per-block survivor staging (16KB LDS)
#define SCAP  (2u<<20)            // 2M survivor entries (16MB, overlays pc)

// ---- MAD / final ----
#define NBM   1024
#define NTM   256
#define NBF   1536
#define NTF   256
#define SP    1048576.f           // 2^20 fixed-point scale for |p-mp|
#define SG    268435456.f         // 2^28 fixed-point scale for |g-mg|

// ---- workspace layout (bytes) ----
#define OFF_H1A  0u                               // uint[65*4096]      ~1.06MB
#define SZ_H1A   (65u*4096u*4u)
#define OFF_H1B  (OFF_H1A + SZ_H1A)               // packed u16[63*65536] = uint[63*32768] ~8.26MB
#define SZ_H1B   (63u*32768u*4u)
#define OFF_H2   (OFF_H1B + SZ_H1B)               // uint[65*8192]      ~2.13MB
#define SZ_H2    (65u*8192u*4u)
#define OFF_PFX  (OFF_H2 + SZ_H2)                 // uint[128] (+pad)
#define OFF_KTH  (OFF_PFX + 512u)
#define OFF_CNT  (OFF_KTH + 512u)
#define OFF_GCT  (OFF_CNT + 512u)
#define OFF_MED  (OFF_GCT + 512u)                 // float[128]
#define OFF_INV  (OFF_MED + 512u)                 // float[128]
#define MEMSET_LEN (OFF_INV + 512u)
#define OFF_PC   ((MEMSET_LEN + 255u) & ~255u)    // uint[NB0*H0SZ] 16MB (fully overwritten)
#define SZ_PC    ((uint)NB0*H0SZ*4u)
#define OFF_GB   OFF_PC                           // uint2[SCAP] 16MB — reuses pc after sel P0
#define OFF_MP   (OFF_PC + SZ_PC)                 // double2[NBM*64]  1MB
#define OFF_FP   (OFF_MP + (uint)NBM*64u*16u)     // float[NBF*64]  384KB

__device__ __forceinline__ uint key_of(float f) {
    uint u = __float_as_uint(f);
    return (u & 0x80000000u) ? ~u : (u | 0x80000000u);
}
__device__ __forceinline__ float val_of(uint k) {
    uint u = (k & 0x80000000u) ? (k & 0x7fffffffu) : ~k;
    return __uint_as_float(u);
}
__device__ __forceinline__ float elem(const float4& v, int j) {
    return (j==0)?v.x:(j==1)?v.y:(j==2)?v.z:v.w;
}

// ================= P0: 7-bit LDS histogram, counts only =================
__global__ __launch_bounds__(NT0) void p0_hist(const float4* __restrict__ pred4,
                                               const float4* __restrict__ gt4,
                                               uint* __restrict__ pcnt, int n4)
{
    __shared__ uint h[H0SZ];
    for (int i = threadIdx.x; i < H0SZ; i += NT0) h[i] = 0u;
    __syncthreads();
    int stride = gridDim.x * blockDim.x;
    for (int i = blockIdx.x*blockDim.x + threadIdx.x; i < n4; i += stride) {
        float4 g4 = gt4[i], p4 = pred4[i];
        #pragma unroll
        for (int j = 0; j < 4; j++) {
            float g = elem(g4,j), p = elem(p4,j);
            if (!(g > 0.f)) continue;
            int bin = (int)(g * 64.f); if (bin > 63) bin = 63;
            uint kp = key_of(p);
            atomicAdd(&h[(uint)bin*ND0 + ((kp>>25) ^ ((uint)bin & 31u))], 1u);
            uint kg = key_of(g);
            uint gr = 64u + (uint)bin;
            uint dg = bin ? ((kg>>16) & 0x7Fu) : (kg>>25);
            atomicAdd(&h[gr*ND0 + (dg ^ (gr & 31u))], 1u);
        }
    }
    __syncthreads();
    uint* dst = pcnt + (size_t)blockIdx.x * H0SZ;
    for (int i = threadIdx.x; i < H0SZ; i += NT0) dst[i] = h[i];
}

// ================= unified select pass (two-phase, rescan) =================
__global__ void sel_pass(const uint* __restrict__ pcnt, const uint* __restrict__ h1A,
                         const uint* __restrict__ h1B, const uint* __restrict__ h2,
                         uint* __restrict__ pfx, uint* __restrict__ kth,
                         uint* __restrict__ cnts, float* __restrict__ meds, int P)
{
    int row = blockIdx.x;                  // P0/P1: 0..127, P2: 0..64
    bool tB = (row >= 65);
    int nd, shift; bool exact;
    const uint* src = nullptr; size_t sbase = 0; bool packed = false;
    if (P == 0)      { nd = ND0; shift = tB ? 16 : 25; exact = false; }
    else if (P == 1) {
        if (tB) { nd = 65536; shift = 0;  exact = true;  src = h1B; sbase = (size_t)(row-65)*32768u; packed = true; }
        else    { nd = 4096;  shift = 13; exact = false; src = h1A; sbase = (size_t)row*4096u; }
    } else           { nd = 8192; shift = 0; exact = true; src = h2; sbase = (size_t)row*8192u; }

    int t = threadIdx.x;                   // 256 threads
    int per = (nd + 255) >> 8;
    int d0 = t * per;

    // phase 1: per-thread digit-range sums
    uint lc = 0;
    for (int j = 0; j < per; j++) {
        int d = d0 + j; if (d >= nd) break;
        uint c;
        if (P == 0) {
            int idx = row*ND0 + (d ^ (row & 31));
            c = 0;
            for (int p = 0; p < NB0; p++) c += pcnt[(size_t)p*H0SZ + idx];
        } else if (packed) c = (src[sbase + (d >> 1)] >> ((d & 1) * 16)) & 0xFFFFu;
        else               c = src[sbase + d];
        lc += c;
    }
    __shared__ uint shc[257];
    shc[t] = lc;
    __syncthreads();
    if (t == 0) { uint r = 0; for (int i = 0; i < 256; i++) { uint c = shc[i]; shc[i] = r; r += c; } shc[256] = r; }
    __syncthreads();
    uint total = shc[256];
    if (P == 0 && t == 0) cnts[row] = total;
    uint k = (P == 0) ? (total ? ((total-1u) >> 1) : 0u) : kth[row];
    if (!total) return;

    // phase 2: owning thread rescans its range
    uint cum = shc[t];
    if (k >= cum && k < cum + lc) {
        for (int j = 0; j < per; j++) {
            int d = d0 + j;
            uint c;
            if (P == 0) {
                int idx = row*ND0 + (d ^ (row & 31));
                c = 0;
                for (int p = 0; p < NB0; p++) c += pcnt[(size_t)p*H0SZ + idx];
            } else if (packed) c = (src[sbase + (d >> 1)] >> ((d & 1) * 16)) & 0xFFFFu;
            else               c = src[sbase + d];
            if (c && k < cum + c) {
                uint np;
                if (P == 0) {
                    uint base = tB ? (key_of((float)(row-64) * 0.015625f) & 0xFF800000u) : 0u;
                    np = base | ((uint)d << shift);
                } else np = pfx[row] | ((uint)d << shift);
                if (!exact) { pfx[row] = np; kth[row] = k - cum; }
                else        meds[row] = val_of(np);
                break;
            }
            cum += c;
        }
    }
}

// ================= P1: filtered hists + type-A survivor compaction =================
__global__ void p1_hist(const float4* __restrict__ pred4, const float4* __restrict__ gt4,
                        const uint* __restrict__ pfx, uint* __restrict__ h1A,
                        uint* __restrict__ h1B, uint2* __restrict__ gbuf,
                        uint* __restrict__ gcnt, int n4)
{
    __shared__ uint2 pft[64];              // (pf[bin], pf[64+bin]) packed -> one b64 gather
    __shared__ uint2 sbuf[LCAP];
    __shared__ uint lcnt, gbase;
    if (threadIdx.x == 0) lcnt = 0u;
    if (threadIdx.x < 64) pft[threadIdx.x] = make_uint2(pfx[threadIdx.x], pfx[64 + threadIdx.x]);
    __syncthreads();

    int stride = gridDim.x * blockDim.x;
    for (int i = blockIdx.x*blockDim.x + threadIdx.x; i < n4; i += stride) {
        float4 g4 = gt4[i], p4 = pred4[i];
        #pragma unroll
        for (int j = 0; j < 4; j++) {
            float g = elem(g4,j), p = elem(p4,j);
            if (!(g > 0.f)) continue;
            int bin = (int)(g * 64.f); if (bin > 63) bin = 63;
            uint2 pf2 = pft[bin];
            uint kp = key_of(p);
            if ((kp & 0xFE000000u) == pf2.x) {
                atomicAdd(&h1A[(size_t)bin*4096 + ((kp>>13) & 0xFFFu)], 1u);
                uint li = atomicAdd(&lcnt, 1u);
                if (li < LCAP) sbuf[li] = make_uint2(kp, (uint)bin);
                else { uint gi = atomicAdd(gcnt, 1u); if (gi < SCAP) gbuf[gi] = make_uint2(kp, (uint)bin); }
            }
            uint kg = key_of(g);
            if (bin == 0) {
                if ((kg & 0xFE000000u) == pf2.y) {
                    atomicAdd(&h1A[(size_t)64*4096 + ((kg>>13) & 0xFFFu)], 1u);
                    uint li = atomicAdd(&lcnt, 1u);
                    if (li < LCAP) sbuf[li] = make_uint2(kg, 64u);
                    else { uint gi = atomicAdd(gcnt, 1u); if (gi < SCAP) gbuf[gi] = make_uint2(kg, 64u); }
                }
            } else {
                if ((kg & 0xFFFF0000u) == pf2.y) {
                    uint d = kg & 0xFFFFu;
                    atomicAdd(&h1B[(size_t)(bin-1)*32768 + (d >> 1)], (d & 1u) ? 65536u : 1u);
                }
            }
        }
    }
    __syncthreads();
    if (threadIdx.x == 0) {
        uint c = lcnt; if (c > LCAP) c = LCAP;
        gbase = atomicAdd(gcnt, c);
    }
    __syncthreads();
    uint c = lcnt; if (c > LCAP) c = LCAP;
    for (uint i = threadIdx.x; i < c; i += blockDim.x) {
        uint gi = gbase + i;
        if (gi < SCAP) gbuf[gi] = sbuf[i];
    }
}

// ================= P2: compacted type-A survivors -> final 13-bit hist =================
__global__ void p2_compact(const uint2* __restrict__ gbuf, const uint* __restrict__ gcnt,
                           const uint* __restrict__ pfx, uint* __restrict__ h2)
{
    uint n = *gcnt; if (n > SCAP) n = SCAP;
    uint stride = gridDim.x * blockDim.x;
    for (uint i = blockIdx.x*blockDim.x + threadIdx.x; i < n; i += stride) {
        uint2 e = gbuf[i];
        if ((e.x & 0xFFFFE000u) == pfx[e.y])
            atomicAdd(&h2[(size_t)e.y*8192 + (e.x & 0x1FFFu)], 1u);
    }
}

// ================= MAD pass: packed u64 fixed-point accumulators =================
__global__ __launch_bounds__(NTM) void mad_pass(const float4* __restrict__ pred4,
                                                const float4* __restrict__ gt4,
                                                const float* __restrict__ meds,
                                                double2* __restrict__ madp, int n4)
{
    __shared__ ull acc[64][64];            // 32KB; low32 = q_p sum, high32 = q_g sum
    __shared__ float2 mm[64];              // (mp[b], mg[b]) -> one b64 gather
    for (int i = threadIdx.x; i < 64*64; i += NTM) ((ull*)acc)[i] = 0ull;
    if (threadIdx.x < 64) mm[threadIdx.x] = make_float2(meds[threadIdx.x], meds[64 + threadIdx.x]);
    __syncthreads();
    const int lane = threadIdx.x & 63;
    int stride = gridDim.x * blockDim.x;
    for (int i = blockIdx.x*blockDim.x + threadIdx.x; i < n4; i += stride) {
        float4 g4 = gt4[i], p4 = pred4[i];
        #pragma unroll
        for (int j = 0; j < 4; j++) {
            float g = elem(g4,j), p = elem(p4,j);
            if (!(g > 0.f)) continue;
            int bin = (int)(g * 64.f); if (bin > 63) bin = 63;
            float2 m = mm[bin];
            uint qp = (uint)(fabsf(p - m.x) * SP + 0.5f);
            uint qg = (uint)(fabsf(g - m.y) * SG + 0.5f);
            atomicAdd(&acc[bin][lane], (ull)qp | ((ull)qg << 32));
        }
    }
    __syncthreads();
    // reduce: thread t -> bin = t>>2, quarter q = t&3 (16 cells each)
    int b = threadIdx.x >> 2, q = threadIdx.x & 3;
    ull lo = 0, hi = 0;
    #pragma unroll
    for (int j = 0; j < 16; j++) {
        ull v = acc[b][q*16 + j];
        lo += (v & 0xFFFFFFFFull); hi += (v >> 32);
    }
    lo += __shfl_xor(lo, 1); lo += __shfl_xor(lo, 2);
    hi += __shfl_xor(hi, 1); hi += __shfl_xor(hi, 2);
    if (q == 0) madp[(size_t)blockIdx.x*64 + b] = make_double2((double)lo, (double)hi);
}

__global__ void sel3(const double2* __restrict__ madp, const uint* __restrict__ cnts,
                     float* __restrict__ inv)
{
    int t = threadIdx.x;                   // 64
    double sp = 0.0, sg = 0.0;
    for (int b = 0; b < NBM; b++) { double2 d = madp[(size_t)b*64 + t]; sp += d.x; sg += d.y; }
    sp /= (double)SP; sg /= (double)SG;
    uint c = cnts[t];
    double mp_ = c ? (sp / (double)c) : 0.0;
    double mg_ = c ? (sg / (double)c) : 0.0;
    inv[t]      = (float)(1.0 / (mp_ + EPSD));
    inv[64 + t] = (float)(1.0 / (mg_ + EPSD));
}

// ================= final |pred_norm - gt_norm| =================
__global__ __launch_bounds__(NTF) void final_pass(const float4* __restrict__ pred4,
                                                  const float4* __restrict__ gt4,
                                                  const float* __restrict__ meds,
                                                  const float* __restrict__ invs,
                                                  float* __restrict__ fpart, int n4)
{
    __shared__ __align__(16) float acc[64][64];    // 16KB, bank = lane%32
    __shared__ float4 tab[64];                     // (ip, ig, C, 0) -> one b128 gather
    for (int i = threadIdx.x; i < 64*64; i += NTF) ((float*)acc)[i] = 0.f;
    if (threadIdx.x < 64) {
        int b = threadIdx.x;
        float ip = invs[b], ig = invs[64 + b];
        tab[b] = make_float4(ip, ig, meds[b]*ip - meds[64 + b]*ig, 0.f);
    }
    __syncthreads();
    const int lane = threadIdx.x & 63;
    int stride = gridDim.x * blockDim.x;
    for (int i = blockIdx.x*blockDim.x + threadIdx.x; i < n4; i += stride) {
        float4 g4 = gt4[i], p4 = pred4[i];
        #pragma unroll
        for (int j = 0; j < 4; j++) {
            float g = elem(g4,j), p = elem(p4,j);
            if (!(g > 0.f)) continue;
            int bin = (int)(g * 64.f); if (bin > 63) bin = 63;
            float4 tb = tab[bin];
            float d = p*tb.x - g*tb.y - tb.z;
            atomicAdd(&acc[bin][lane], fabsf(d));
        }
    }
    __syncthreads();
    const float4* a4 = (const float4*)&acc[0][0];
    #pragma unroll
    for (int it = 0; it < (64*64/4)/NTF; ++it) {
        int f = it*NTF + threadIdx.x;
        float4 v = a4[f];
        float s = v.x + v.y + v.z + v.w;
        s += __shfl_xor(s, 1); s += __shfl_xor(s, 2);
        s += __shfl_xor(s, 4); s += __shfl_xor(s, 8);
        if ((f & 15) == 0) fpart[(size_t)blockIdx.x*64 + (f >> 4)] = s;
    }
}

__global__ void finish_kernel(const float* __restrict__ fpart, const uint* __restrict__ cnts,
                              float* __restrict__ out)
{
    __shared__ double sh[64];
    int t = threadIdx.x;                   // 64
    double s = 0.0;
    for (int b = 0; b < NBF; b++) s += (double)fpart[(size_t)b*64 + t];
    uint c = cnts[t];
    sh[t] = c ? (s / (double)c) : 0.0;
    __syncthreads();
    for (int o = 32; o; o >>= 1) { if (t < o) sh[t] += sh[t + o]; __syncthreads(); }
    if (t == 0) out[0] = (float)(sh[0] / 64.0);
}

extern "C" void kernel_launch(void* const* d_in, const int* in_sizes, int n_in,
                              void* d_out, int out_size, void* d_ws, size_t ws_size,
                              hipStream_t stream)
{
    const float* pred = (const float*)d_in[0];
    const float* gt   = (const float*)d_in[1];
    int n  = in_sizes[0];
    int n4 = n >> 2;

    unsigned char* ws = (unsigned char*)d_ws;
    uint*    h1A  = (uint*)   (ws + OFF_H1A);
    uint*    h1B  = (uint*)   (ws + OFF_H1B);
    uint*    h2   = (uint*)   (ws + OFF_H2);
    uint*    pfx  = (uint*)   (ws + OFF_PFX);
    uint*    kth  = (uint*)   (ws + OFF_KTH);
    uint*    cnt  = (uint*)   (ws + OFF_CNT);
    uint*    gct  = (uint*)   (ws + OFF_GCT);
    float*   med  = (float*)  (ws + OFF_MED);
    float*   inv  = (float*)  (ws + OFF_INV);
    uint*    pc   = (uint*)   (ws + OFF_PC);
    uint2*   gb   = (uint2*)  (ws + OFF_GB);
    double2* mp   = (double2*)(ws + OFF_MP);
    float*   fp   = (float*)  (ws + OFF_FP);
    float*   out  = (float*)  d_out;

    hipMemsetAsync(ws, 0, MEMSET_LEN, stream);

    p0_hist<<<NB0, NT0, 0, stream>>>((const float4*)pred, (const float4*)gt, pc, n4);
    sel_pass<<<128, 256, 0, stream>>>(pc, h1A, h1B, h2, pfx, kth, cnt, med, 0);
    p1_hist<<<NB1, 256, 0, stream>>>((const float4*)pred, (const float4*)gt, pfx, h1A, h1B, gb, gct, n4);
    sel_pass<<<128, 256, 0, stream>>>(pc, h1A, h1B, h2, pfx, kth, cnt, med, 1);
    p2_compact<<<256, 256, 0, stream>>>(gb, gct, pfx, h2);
    sel_pass<<<65, 256, 0, stream>>>(pc, h1A, h1B, h2, pfx, kth, cnt, med, 2);
    mad_pass<<<NBM, NTM, 0, stream>>>((const float4*)pred, (const float4*)gt, med, mp, n4);
    sel3<<<1, 64, 0, stream>>>(mp, cnt, inv);
    final_pass<<<NBF, NTF, 0, stream>>>((const float4*)pred, (const float4*)gt, med, inv, fp, n4);
    finish_kernel<<<1, 64, 0, stream>>>(fp, cnt, out);
}